// Round 5
// baseline (130.309 us; speedup 1.0000x reference)
//
#include <hip/hip_runtime.h>
#include <hip/hip_bf16.h>

// SpatialAttention: out[b,i,j] = softmax_j( sum_c w3[c] * tanh(x1[b,i,c] + x2[b,j,c]) )
// x1 = x@W1^T, x2 = x@W2^T.  B=4, N=1024, C=64.
//
// tanh(s) = 1 - 2/(exp2(K2*s)+1), K2 = 2*log2(e); exp2 factorizes:
// exp2(K2*(x1+x2)) = e1*e2, e1/e2 precomputed in proj (clamped to 2^15 each).
// att = sum(w3) - 2 * sum_c w3[c] * rcp(fma(e1,e2,1)).
// Paired reciprocal over the i-pair: r = rcp(da*db); t = w3c*r;
// acc.x += db*t; acc.y += da*t   (6 full-rate + 1 trans per 2 elements).
//
// R5: R4 was latency-bound (VALUBusy 49%, occupancy 27%, 4 blocks/CU cap).
// attn: TI=2, grid 2048 -> 8 blocks/CU = 32 waves/CU occupancy cap (VGPR ~40,
// LDS 8.7 KB don't cap).  proj: 16 rows/block, grid 256, W staged transposed
// once per 16 rows (~1 us total).

#define BATCH 4
#define NN    1024
#define CC    64
#define TI    2              // rows i per attn block
#define BLK   256
#define J2    2              // j's per thread
#define NCH   (NN / (BLK * J2))   // 2 chunks
#define PP    65             // padded pitch for transposed W in LDS
#define PROWS 16             // rows per proj block

__device__ __forceinline__ float fast_exp2(float x) {
#if __has_builtin(__builtin_amdgcn_exp2f)
    return __builtin_amdgcn_exp2f(x);
#else
    return exp2f(x);
#endif
}
__device__ __forceinline__ float fast_rcp(float x) {
#if __has_builtin(__builtin_amdgcn_rcpf)
    return __builtin_amdgcn_rcpf(x);
#else
    return 1.0f / x;
#endif
}

// ---------------- Kernel 1: projections -> exp2 factors ---------------------
// grid 256 x 256 thr; block handles rows r0..r0+15; wave w does 4 rows.
__global__ __launch_bounds__(256) void proj_kernel(
    const float* __restrict__ x, const float* __restrict__ W1,
    const float* __restrict__ W2, float* __restrict__ e1p,
    float* __restrict__ e2p) {
    __shared__ float w1t[CC * PP];        // [c][d] transposed, 16.25 KB
    __shared__ float w2t[CC * PP];
    __shared__ float xs[PROWS * CC];      // [r][c] straight, 4 KB

    const int tid = threadIdx.x;
    const int r0  = blockIdx.x * PROWS;
    {   // W: coalesced load + transpose into LDS
        const float4* __restrict__ W1v = (const float4*)W1;
        const float4* __restrict__ W2v = (const float4*)W2;
#pragma unroll
        for (int k = 0; k < 4; ++k) {
            const int fi = k * 256 + tid;      // float4 index in [0,1024)
            const int r  = fi >> 4;            // row d
            const int c4 = (fi & 15) * 4;      // col c base
            float4 a = W1v[fi], b = W2v[fi];
            w1t[(c4 + 0) * PP + r] = a.x; w1t[(c4 + 1) * PP + r] = a.y;
            w1t[(c4 + 2) * PP + r] = a.z; w1t[(c4 + 3) * PP + r] = a.w;
            w2t[(c4 + 0) * PP + r] = b.x; w2t[(c4 + 1) * PP + r] = b.y;
            w2t[(c4 + 2) * PP + r] = b.z; w2t[(c4 + 3) * PP + r] = b.w;
        }
        // x tile: coalesced, conflict-free
        const int rr = tid >> 6, c = tid & 63;
#pragma unroll
        for (int k = 0; k < 4; ++k) {
            const int r = k * 4 + rr;
            xs[r * CC + c] = x[(size_t)(r0 + r) * CC + c];
        }
    }
    __syncthreads();

    const int w    = tid >> 6;
    const int lane = tid & 63;
    const int rb   = w * 4;               // this wave's 4 rows (in-block)

    float a1[4] = {0.f, 0.f, 0.f, 0.f};
    float a2[4] = {0.f, 0.f, 0.f, 0.f};
#pragma unroll
    for (int c = 0; c < CC; ++c) {
        const float w1v = w1t[c * PP + lane];
        const float w2v = w2t[c * PP + lane];
        const float x0 = xs[(rb + 0) * CC + c];   // broadcast reads
        const float x1 = xs[(rb + 1) * CC + c];
        const float x2v = xs[(rb + 2) * CC + c];
        const float x3 = xs[(rb + 3) * CC + c];
        a1[0] = fmaf(x0, w1v, a1[0]);  a2[0] = fmaf(x0, w2v, a2[0]);
        a1[1] = fmaf(x1, w1v, a1[1]);  a2[1] = fmaf(x1, w2v, a2[1]);
        a1[2] = fmaf(x2v, w1v, a1[2]); a2[2] = fmaf(x2v, w2v, a2[2]);
        a1[3] = fmaf(x3, w1v, a1[3]);  a2[3] = fmaf(x3, w2v, a2[3]);
    }
    const float K2 = 2.8853900817779268f;  // 2*log2(e)
#pragma unroll
    for (int rr = 0; rr < 4; ++rr) {
        const size_t r = (size_t)(r0 + rb + rr);
        e1p[r * CC + lane] = fast_exp2(fminf(a1[rr] * K2, 15.f));
        e2p[r * CC + lane] = fast_exp2(fminf(a2[rr] * K2, 15.f));
    }
}

// ---------------- Kernel 2: fused att + softmax -----------------------------
// paired reciprocal for the i-pair, one j (2 elements):
__device__ __forceinline__ void step2(float e1a, float e1b, float e2,
                                      float wc, float2& acc) {
    float da = fmaf(e1a, e2, 1.f);
    float db = fmaf(e1b, e2, 1.f);
    float r  = fast_rcp(da * db);
    float t  = wc * r;
    acc.x = fmaf(db, t, acc.x);   // w3c / da
    acc.y = fmaf(da, t, acc.y);   // w3c / db
}

__global__ __launch_bounds__(BLK) void attn_kernel(
    const float* __restrict__ e1p, const float* __restrict__ e2p,
    const float* __restrict__ w3, float* __restrict__ out) {
    __shared__ float e1t[CC * TI];          // [c][i] transposed: 512 B
    __shared__ float att_lds[TI * NN];      // 8 KB

    const int tid = threadIdx.x;
    const int bi  = blockIdx.x;             // 2048 blocks
    const int b   = bi >> 9;                // 512 blocks per batch
    const int i0  = (bi & 511) * TI;

    if (tid < CC * TI) {                    // stage e1 pair transposed
        const int ii = tid >> 6, c = tid & 63;
        e1t[c * TI + ii] = e1p[(size_t)((b << 10) + i0 + ii) * CC + c];
    }
    __syncthreads();

    // w3: uniform address -> scalar loads; also its sum
    const float4* __restrict__ w3q = (const float4*)w3;
    float sumw3 = 0.f;
#pragma unroll
    for (int q = 0; q < 16; ++q) {
        float4 t = w3q[q];
        sumw3 += (t.x + t.y) + (t.z + t.w);
    }

    const float* __restrict__ e2b = e2p + ((size_t)b << 10) * CC;
    const float2* e1t2 = (const float2*)e1t;   // [c] -> i-pair (broadcast)

#pragma unroll 1
    for (int ch = 0; ch < NCH; ++ch) {
        const int j0 = ch * (BLK * J2) + tid;          // j1 = j0 + BLK
        const float4* __restrict__ rowA = (const float4*)(e2b + (size_t)j0 * CC);
        const float4* __restrict__ rowB = rowA + (BLK * CC / 4);

        float2 accA = {0.f, 0.f}, accB = {0.f, 0.f};

#pragma unroll 1
        for (int ct = 0; ct < 4; ++ct) {               // 4 c-tiles of 16
#pragma unroll
            for (int q = 0; q < 4; ++q) {
                const float4 eAv = rowA[ct * 4 + q];
                const float4 eBv = rowB[ct * 4 + q];
                const float4 wv  = w3q[ct * 4 + q];    // s_load (uniform)
                const float eAa[4] = {eAv.x, eAv.y, eAv.z, eAv.w};
                const float eBa[4] = {eBv.x, eBv.y, eBv.z, eBv.w};
                const float wa[4]  = {wv.x, wv.y, wv.z, wv.w};
#pragma unroll
                for (int m = 0; m < 4; ++m) {
                    const int c = ct * 16 + q * 4 + m;
                    const float2 ev = e1t2[c];         // LDS broadcast b64
                    step2(ev.x, ev.y, eAa[m], wa[m], accA);
                    step2(ev.x, ev.y, eBa[m], wa[m], accB);
                }
            }
        }
        const int j1 = j0 + BLK;
        att_lds[0 * NN + j0] = fmaf(-2.f, accA.x, sumw3);
        att_lds[1 * NN + j0] = fmaf(-2.f, accA.y, sumw3);
        att_lds[0 * NN + j1] = fmaf(-2.f, accB.x, sumw3);
        att_lds[1 * NN + j1] = fmaf(-2.f, accB.y, sumw3);
    }
    __syncthreads();

    // epilogue: wave w (w < TI) softmaxes row i0+w over j
    {
        const int w    = tid >> 6;
        const int lane = tid & 63;
        if (w < TI) {
            float v[16];
            float m = -3.4e38f;
#pragma unroll
            for (int k = 0; k < 16; ++k) {
                v[k] = att_lds[w * NN + k * 64 + lane];
                m = fmaxf(m, v[k]);
            }
#pragma unroll
            for (int off = 32; off >= 1; off >>= 1)
                m = fmaxf(m, __shfl_xor(m, off));
            const float L2E = 1.4426950408889634f;
            float s = 0.f;
#pragma unroll
            for (int k = 0; k < 16; ++k) {
                v[k] = fast_exp2((v[k] - m) * L2E);
                s += v[k];
            }
#pragma unroll
            for (int off = 32; off >= 1; off >>= 1)
                s += __shfl_xor(s, off);
            const float rs = fast_rcp(s);
            float* __restrict__ orow = out + (((size_t)(b << 10) + (i0 + w)) << 10);
#pragma unroll
            for (int k = 0; k < 16; ++k) orow[k * 64 + lane] = v[k] * rs;
        }
    }
}

extern "C" void kernel_launch(void* const* d_in, const int* in_sizes, int n_in,
                              void* d_out, int out_size, void* d_ws, size_t ws_size,
                              hipStream_t stream) {
    const float* x  = (const float*)d_in[0];
    const float* W1 = (const float*)d_in[1];
    const float* W2 = (const float*)d_in[2];
    const float* w3 = (const float*)d_in[3];
    float* outp = (float*)d_out;

    float* e1p = (float*)d_ws;                       // 4096*64 fp32 = 1 MB
    float* e2p = e1p + (size_t)BATCH * NN * CC;      // second 1 MB

    proj_kernel<<<dim3(BATCH * NN / PROWS), dim3(256), 0, stream>>>(x, W1, W2, e1p, e2p);
    attn_kernel<<<dim3(BATCH * NN / TI), dim3(BLK), 0, stream>>>(e1p, e2p, w3, outp);
}

// Round 6
// 102.739 us; speedup vs baseline: 1.2683x; 1.2683x over previous
//
#include <hip/hip_runtime.h>
#include <hip/hip_bf16.h>

// SpatialAttention: out[b,i,j] = softmax_j( sum_c w3[c] * tanh(x1[b,i,c] + x2[b,j,c]) )
// x1 = x@W1^T, x2 = x@W2^T.  B=4, N=1024, C=64.
//
// tanh(s) = 1 - 2/(exp2(K2*s)+1), K2 = 2*log2(e); exp2 factorizes:
// exp2(K2*(x1+x2)) = e1*e2, precomputed in proj (each clamped to 2^15).
// att = sum(w3) - 2 * sum_c w3[c] * rcp(fma(e1,e2,1)).
// Paired reciprocal over the i-pair: r = rcp(da*db); t = w3c*r;
// acc.x += db*t; acc.y += da*t   (6 full-rate + 1 trans per 2 elements).
//
// R6: R5 (TI=2, 2048 small blocks) regressed — halved amortization doubled
// L2 traffic + per-block overhead.  This round: TI=4, BLK=512, grid=1024:
// same 8:1 step2:load amortization as R4 but 8 waves/block -> 4 blocks/CU
// x 8 waves = 32 waves/CU occupancy CAP = 100% (R4 capped at 50%).
// VGPR kept <= 64 (no prefetch arrays) to stay on the 8-wave/SIMD bin.

#define BATCH 4
#define NN    1024
#define CC    64
#define TI    4              // rows i per attn block
#define BLK   512
#define NCH   (NN / BLK)     // 2 chunks, 1 j per thread per chunk
#define PP    65             // padded pitch for transposed W in LDS
#define PROWS 16             // rows per proj block

__device__ __forceinline__ float fast_exp2(float x) {
#if __has_builtin(__builtin_amdgcn_exp2f)
    return __builtin_amdgcn_exp2f(x);
#else
    return exp2f(x);
#endif
}
__device__ __forceinline__ float fast_rcp(float x) {
#if __has_builtin(__builtin_amdgcn_rcpf)
    return __builtin_amdgcn_rcpf(x);
#else
    return 1.0f / x;
#endif
}

// ---------------- Kernel 1: projections -> exp2 factors ---------------------
// grid 256 x 256 thr; block handles rows r0..r0+15; wave w does 4 rows.
__global__ __launch_bounds__(256) void proj_kernel(
    const float* __restrict__ x, const float* __restrict__ W1,
    const float* __restrict__ W2, float* __restrict__ e1p,
    float* __restrict__ e2p) {
    __shared__ float w1t[CC * PP];        // [c][d] transposed, 16.25 KB
    __shared__ float w2t[CC * PP];
    __shared__ float xs[PROWS * CC];      // [r][c] straight, 4 KB

    const int tid = threadIdx.x;
    const int r0  = blockIdx.x * PROWS;
    {   // W: coalesced load + transpose into LDS
        const float4* __restrict__ W1v = (const float4*)W1;
        const float4* __restrict__ W2v = (const float4*)W2;
#pragma unroll
        for (int k = 0; k < 4; ++k) {
            const int fi = k * 256 + tid;      // float4 index in [0,1024)
            const int r  = fi >> 4;            // row d
            const int c4 = (fi & 15) * 4;      // col c base
            float4 a = W1v[fi], b = W2v[fi];
            w1t[(c4 + 0) * PP + r] = a.x; w1t[(c4 + 1) * PP + r] = a.y;
            w1t[(c4 + 2) * PP + r] = a.z; w1t[(c4 + 3) * PP + r] = a.w;
            w2t[(c4 + 0) * PP + r] = b.x; w2t[(c4 + 1) * PP + r] = b.y;
            w2t[(c4 + 2) * PP + r] = b.z; w2t[(c4 + 3) * PP + r] = b.w;
        }
        // x tile: coalesced, conflict-free
        const int rr = tid >> 6, c = tid & 63;
#pragma unroll
        for (int k = 0; k < 4; ++k) {
            const int r = k * 4 + rr;
            xs[r * CC + c] = x[(size_t)(r0 + r) * CC + c];
        }
    }
    __syncthreads();

    const int w    = tid >> 6;
    const int lane = tid & 63;
    const int rb   = w * 4;               // this wave's 4 rows (in-block)

    float a1[4] = {0.f, 0.f, 0.f, 0.f};
    float a2[4] = {0.f, 0.f, 0.f, 0.f};
#pragma unroll
    for (int c = 0; c < CC; ++c) {
        const float w1v = w1t[c * PP + lane];
        const float w2v = w2t[c * PP + lane];
        const float x0 = xs[(rb + 0) * CC + c];   // broadcast reads
        const float x1 = xs[(rb + 1) * CC + c];
        const float x2v = xs[(rb + 2) * CC + c];
        const float x3 = xs[(rb + 3) * CC + c];
        a1[0] = fmaf(x0, w1v, a1[0]);  a2[0] = fmaf(x0, w2v, a2[0]);
        a1[1] = fmaf(x1, w1v, a1[1]);  a2[1] = fmaf(x1, w2v, a2[1]);
        a1[2] = fmaf(x2v, w1v, a1[2]); a2[2] = fmaf(x2v, w2v, a2[2]);
        a1[3] = fmaf(x3, w1v, a1[3]);  a2[3] = fmaf(x3, w2v, a2[3]);
    }
    const float K2 = 2.8853900817779268f;  // 2*log2(e)
#pragma unroll
    for (int rr = 0; rr < 4; ++rr) {
        const size_t r = (size_t)(r0 + rb + rr);
        e1p[r * CC + lane] = fast_exp2(fminf(a1[rr] * K2, 15.f));
        e2p[r * CC + lane] = fast_exp2(fminf(a2[rr] * K2, 15.f));
    }
}

// ---------------- Kernel 2: fused att + softmax -----------------------------
// paired reciprocal for one i-pair, one j (2 elements):
__device__ __forceinline__ void step2(float e1a, float e1b, float e2,
                                      float wc, float2& acc) {
    float da = fmaf(e1a, e2, 1.f);
    float db = fmaf(e1b, e2, 1.f);
    float r  = fast_rcp(da * db);
    float t  = wc * r;
    acc.x = fmaf(db, t, acc.x);   // w3c / da
    acc.y = fmaf(da, t, acc.y);   // w3c / db
}

__global__ __launch_bounds__(BLK) void attn_kernel(
    const float* __restrict__ e1p, const float* __restrict__ e2p,
    const float* __restrict__ w3, float* __restrict__ out) {
    __shared__ float e1t[CC * TI];          // [c][i] transposed: 1 KB
    __shared__ float att_lds[TI * NN];      // 16 KB

    const int tid = threadIdx.x;
    const int bi  = blockIdx.x;             // 1024 blocks
    const int b   = bi >> 8;                // 256 blocks per batch
    const int i0  = (bi & 255) * TI;

    if (tid < CC * TI) {                    // stage e1 tile transposed
        const int ii = tid >> 6, c = tid & 63;
        e1t[c * TI + ii] = e1p[(size_t)((b << 10) + i0 + ii) * CC + c];
    }
    __syncthreads();

    // w3: uniform address -> scalar loads; also its sum
    const float4* __restrict__ w3q = (const float4*)w3;
    float sumw3 = 0.f;
#pragma unroll
    for (int q = 0; q < 16; ++q) {
        float4 t = w3q[q];
        sumw3 += (t.x + t.y) + (t.z + t.w);
    }

    const float* __restrict__ e2b = e2p + ((size_t)b << 10) * CC;
    const float4* e1t4 = (const float4*)e1t;   // [c] -> 4 i's (broadcast)

#pragma unroll 1
    for (int ch = 0; ch < NCH; ++ch) {
        const int j = ch * BLK + tid;
        const float4* __restrict__ row = (const float4*)(e2b + (size_t)j * CC);

        float2 accA = {0.f, 0.f};   // i0, i1
        float2 accB = {0.f, 0.f};   // i2, i3

#pragma unroll 1
        for (int ct = 0; ct < 4; ++ct) {               // 4 c-tiles of 16
#pragma unroll
            for (int q = 0; q < 4; ++q) {
                const float4 ev2 = row[ct * 4 + q];    // own j row (VMEM)
                const float4 wv  = w3q[ct * 4 + q];    // s_load (uniform)
                const float ea[4] = {ev2.x, ev2.y, ev2.z, ev2.w};
                const float wa[4] = {wv.x, wv.y, wv.z, wv.w};
#pragma unroll
                for (int m = 0; m < 4; ++m) {
                    const int c = ct * 16 + q * 4 + m;
                    const float4 ev = e1t4[c];         // LDS broadcast b128
                    step2(ev.x, ev.y, ea[m], wa[m], accA);
                    step2(ev.z, ev.w, ea[m], wa[m], accB);
                }
            }
        }
        att_lds[0 * NN + j] = fmaf(-2.f, accA.x, sumw3);
        att_lds[1 * NN + j] = fmaf(-2.f, accA.y, sumw3);
        att_lds[2 * NN + j] = fmaf(-2.f, accB.x, sumw3);
        att_lds[3 * NN + j] = fmaf(-2.f, accB.y, sumw3);
    }
    __syncthreads();

    // epilogue: wave w (w < TI) softmaxes row i0+w over j
    {
        const int w    = tid >> 6;
        const int lane = tid & 63;
        if (w < TI) {
            float v[16];
            float m = -3.4e38f;
#pragma unroll
            for (int k = 0; k < 16; ++k) {
                v[k] = att_lds[w * NN + k * 64 + lane];
                m = fmaxf(m, v[k]);
            }
#pragma unroll
            for (int off = 32; off >= 1; off >>= 1)
                m = fmaxf(m, __shfl_xor(m, off));
            const float L2E = 1.4426950408889634f;
            float s = 0.f;
#pragma unroll
            for (int k = 0; k < 16; ++k) {
                v[k] = fast_exp2((v[k] - m) * L2E);
                s += v[k];
            }
#pragma unroll
            for (int off = 32; off >= 1; off >>= 1)
                s += __shfl_xor(s, off);
            const float rs = fast_rcp(s);
            float* __restrict__ orow = out + (((size_t)(b << 10) + (i0 + w)) << 10);
#pragma unroll
            for (int k = 0; k < 16; ++k) orow[k * 64 + lane] = v[k] * rs;
        }
    }
}

extern "C" void kernel_launch(void* const* d_in, const int* in_sizes, int n_in,
                              void* d_out, int out_size, void* d_ws, size_t ws_size,
                              hipStream_t stream) {
    const float* x  = (const float*)d_in[0];
    const float* W1 = (const float*)d_in[1];
    const float* W2 = (const float*)d_in[2];
    const float* w3 = (const float*)d_in[3];
    float* outp = (float*)d_out;

    float* e1p = (float*)d_ws;                       // 4096*64 fp32 = 1 MB
    float* e2p = e1p + (size_t)BATCH * NN * CC;      // second 1 MB

    proj_kernel<<<dim3(BATCH * NN / PROWS), dim3(256), 0, stream>>>(x, W1, W2, e1p, e2p);
    attn_kernel<<<dim3(BATCH * NN / TI), dim3(BLK), 0, stream>>>(e1p, e2p, w3, outp);
}